// Round 1
// baseline (244.839 us; speedup 1.0000x reference)
//
#include <hip/hip_runtime.h>
#include <hip/hip_bf16.h>

// DeepseekV2 MoE layer: M=1024 tokens, H=1024 hidden, E=16 experts (top-6 of
// 8 groups-of-2 -> top-3 groups), N=1024 per-expert intermediate, shared
// expert with I=2048. All inputs fp32; GEMMs run bf16 MFMA (threshold 2.2e-2).

#define M_TOK 1024
#define HDIM  1024
#define NEXP  16
#define NMOE  1024
#define NSH   2048

using bf16x8 = __attribute__((ext_vector_type(8))) short;
using f32x4  = __attribute__((ext_vector_type(4))) float;

static __device__ __forceinline__ short f2b(float x) {
  __hip_bfloat16 b = __float2bfloat16(x);
  return __builtin_bit_cast(short, b);
}

// ---------------- router: logits + softmax + grouped top-k ----------------
__global__ __launch_bounds__(256)
void k_router(const float* __restrict__ hs, const float* __restrict__ gw,
              float* __restrict__ comb, unsigned* __restrict__ maskbuf) {
  int wave = threadIdx.x >> 6, lane = threadIdx.x & 63;
  int tok = blockIdx.x * 4 + wave;
  const float* hrow = hs + (size_t)tok * HDIM;
  float acc[16];
#pragma unroll
  for (int e = 0; e < 16; e++) acc[e] = 0.f;
  for (int h0 = 0; h0 < HDIM; h0 += 64) {
    float x = hrow[h0 + lane];
#pragma unroll
    for (int e = 0; e < 16; e++) acc[e] = fmaf(x, gw[e * HDIM + h0 + lane], acc[e]);
  }
#pragma unroll
  for (int e = 0; e < 16; e++) {
    float v = acc[e];
#pragma unroll
    for (int off = 32; off; off >>= 1) v += __shfl_xor(v, off);
    acc[e] = v;
  }
  // fp32 softmax (selection must match fp32 reference)
  float mx = acc[0];
#pragma unroll
  for (int e = 1; e < 16; e++) mx = fmaxf(mx, acc[e]);
  float sum = 0.f;
#pragma unroll
  for (int e = 0; e < 16; e++) { acc[e] = __expf(acc[e] - mx); sum += acc[e]; }
  float inv = 1.f / sum;
#pragma unroll
  for (int e = 0; e < 16; e++) acc[e] *= inv;
  // group scores: 8 groups of 2 consecutive experts
  float gs[8];
#pragma unroll
  for (int g = 0; g < 8; g++) gs[g] = fmaxf(acc[2 * g], acc[2 * g + 1]);
  // top-3 groups, ties -> lowest index (strict >)
  unsigned gmask = 0;
  for (int t = 0; t < 3; t++) {
    int best = 0; float bv = -1.f;
#pragma unroll
    for (int g = 0; g < 8; g++) {
      bool take = (((gmask >> g) & 1u) == 0u) && (gs[g] > bv);
      bv = take ? gs[g] : bv;
      best = take ? g : best;
    }
    gmask |= 1u << best;
  }
  unsigned emask = 0;
#pragma unroll
  for (int g = 0; g < 8; g++) if ((gmask >> g) & 1u) emask |= 3u << (2 * g);
  if (lane < 16) comb[tok * 16 + lane] = ((emask >> lane) & 1u) ? acc[lane] : 0.f;
  if (lane == 0) maskbuf[tok] = emask;
}

// ---------------- per-expert token list compaction ----------------
__global__ __launch_bounds__(1024)
void k_build_lists(const unsigned* __restrict__ maskbuf, int* __restrict__ lists,
                   int* __restrict__ counts, int* __restrict__ offsets) {
  int e = threadIdx.x >> 6, lane = threadIdx.x & 63;
  int cnt = 0;
  for (int c = 0; c < 16; c++) {
    int tok = c * 64 + lane;
    bool sel = (maskbuf[tok] >> e) & 1u;
    unsigned long long b = __ballot(sel);
    if (sel) {
      int pos = cnt + __popcll(b & ((1ull << lane) - 1ull));
      lists[e * 1024 + pos] = tok;
    }
    cnt += __popcll(b);
  }
  for (int i = cnt + lane; i < 1024; i += 64) lists[e * 1024 + i] = 0;  // safe tail
  if (lane == 0) counts[e] = cnt;
  __syncthreads();
  if (threadIdx.x == 0) {
    int run = 0;
    for (int ee = 0; ee < 16; ee++) { offsets[ee] = run; run += counts[ee]; }
  }
}

// ---------------- GEMM1: g = silu(A@Wg^T) * (A@Wu^T), bf16 out ----------------
// block tile: 128 rows x 64 g-cols, BK=32, 4 waves (2x2), wave tile 64x32.
__global__ __launch_bounds__(256)
void k_mlp1(const float* __restrict__ A, const float* __restrict__ W,
            __hip_bfloat16* __restrict__ G,
            const int* __restrict__ lists, const int* __restrict__ counts,
            const int* __restrict__ offsets, int N) {
  const int H = HDIM;
  int e = blockIdx.z;
  int n0 = blockIdx.x * 64;
  int m0 = blockIdx.y * 128;
  int count = lists ? counts[e] : M_TOK;
  if (m0 >= count) return;
  int gbase = (lists ? offsets[e] : 0) + m0;
  const float* We = W + (size_t)e * (2 * (size_t)N) * H;

  __shared__ short sA[128 * 32];
  __shared__ short sBg[64 * 32];
  __shared__ short sBu[64 * 32];
  __shared__ int sTok[128];

  int tid = threadIdx.x;
  if (tid < 128) sTok[tid] = lists ? lists[e * 1024 + m0 + tid] : (m0 + tid);
  __syncthreads();

  int r0 = tid >> 3, c4 = (tid & 7) * 4;
  const float* pA[4];
#pragma unroll
  for (int i = 0; i < 4; i++) pA[i] = A + (size_t)sTok[r0 + i * 32] * H + c4;
  const float* pBg[2]; const float* pBu[2];
#pragma unroll
  for (int i = 0; i < 2; i++) {
    pBg[i] = We + (size_t)(n0 + r0 + i * 32) * H + c4;
    pBu[i] = We + ((size_t)N + n0 + r0 + i * 32) * H + c4;
  }

  int wave = tid >> 6, lane = tid & 63;
  int wm = wave >> 1, wn = wave & 1;
  int lrow = lane & 15, lquad = lane >> 4;

  f32x4 acc1[4][2] = {};
  f32x4 acc2[4][2] = {};

  for (int k0 = 0; k0 < H; k0 += 32) {
    float4 va[4], vg[2], vu[2];
#pragma unroll
    for (int i = 0; i < 4; i++) va[i] = *reinterpret_cast<const float4*>(pA[i] + k0);
#pragma unroll
    for (int i = 0; i < 2; i++) {
      vg[i] = *reinterpret_cast<const float4*>(pBg[i] + k0);
      vu[i] = *reinterpret_cast<const float4*>(pBu[i] + k0);
    }
    __syncthreads();
#pragma unroll
    for (int i = 0; i < 4; i++) {
      short4 s; s.x = f2b(va[i].x); s.y = f2b(va[i].y); s.z = f2b(va[i].z); s.w = f2b(va[i].w);
      *reinterpret_cast<short4*>(&sA[(r0 + i * 32) * 32 + c4]) = s;
    }
#pragma unroll
    for (int i = 0; i < 2; i++) {
      short4 s; s.x = f2b(vg[i].x); s.y = f2b(vg[i].y); s.z = f2b(vg[i].z); s.w = f2b(vg[i].w);
      *reinterpret_cast<short4*>(&sBg[(r0 + i * 32) * 32 + c4]) = s;
      short4 u; u.x = f2b(vu[i].x); u.y = f2b(vu[i].y); u.z = f2b(vu[i].z); u.w = f2b(vu[i].w);
      *reinterpret_cast<short4*>(&sBu[(r0 + i * 32) * 32 + c4]) = u;
    }
    __syncthreads();
    bf16x8 af[4], bg[2], bu[2];
#pragma unroll
    for (int i = 0; i < 4; i++)
      af[i] = *reinterpret_cast<const bf16x8*>(&sA[(wm * 64 + i * 16 + lrow) * 32 + lquad * 8]);
#pragma unroll
    for (int i = 0; i < 2; i++) {
      bg[i] = *reinterpret_cast<const bf16x8*>(&sBg[(wn * 32 + i * 16 + lrow) * 32 + lquad * 8]);
      bu[i] = *reinterpret_cast<const bf16x8*>(&sBu[(wn * 32 + i * 16 + lrow) * 32 + lquad * 8]);
    }
#pragma unroll
    for (int mi = 0; mi < 4; mi++)
#pragma unroll
      for (int ni = 0; ni < 2; ni++) {
        acc1[mi][ni] = __builtin_amdgcn_mfma_f32_16x16x32_bf16(af[mi], bg[ni], acc1[mi][ni], 0, 0, 0);
        acc2[mi][ni] = __builtin_amdgcn_mfma_f32_16x16x32_bf16(af[mi], bu[ni], acc2[mi][ni], 0, 0, 0);
      }
  }
#pragma unroll
  for (int mi = 0; mi < 4; mi++)
#pragma unroll
    for (int r = 0; r < 4; r++) {
      int li = wm * 64 + mi * 16 + lquad * 4 + r;
      if (m0 + li < count) {
#pragma unroll
        for (int ni = 0; ni < 2; ni++) {
          float x = acc1[mi][ni][r], y = acc2[mi][ni][r];
          float gv = (x / (1.f + __expf(-x))) * y;
          G[(size_t)(gbase + li) * N + (n0 + wn * 32 + ni * 16 + lrow)] = __float2bfloat16(gv);
        }
      }
    }
}

// ---------------- GEMM2: out = g @ W2^T (store or weighted atomic-add) ----------------
__global__ __launch_bounds__(256)
void k_mlp2(const __hip_bfloat16* __restrict__ Gm, const float* __restrict__ W2,
            float* __restrict__ out,
            const int* __restrict__ lists, const int* __restrict__ counts,
            const int* __restrict__ offsets, const float* __restrict__ comb,
            int K, int mode) {
  int e = blockIdx.z;
  int h0 = blockIdx.x * 64;
  int m0 = blockIdx.y * 128;
  int count = lists ? counts[e] : M_TOK;
  if (m0 >= count) return;
  int abase = (lists ? offsets[e] : 0) + m0;
  const float* We = W2 + (size_t)e * HDIM * K;

  __shared__ short sA[128 * 32];
  __shared__ short sB[64 * 32];
  __shared__ int sTok[128];

  int tid = threadIdx.x;
  if (tid < 128) sTok[tid] = lists ? lists[e * 1024 + m0 + tid] : (m0 + tid);
  __syncthreads();

  int ra = tid >> 2, ca = (tid & 3) * 8;  // bf16 A: 16B chunks
  const __hip_bfloat16* pA0 = Gm + (size_t)(abase + ra) * K + ca;
  const __hip_bfloat16* pA1 = Gm + (size_t)(abase + ra + 64) * K + ca;
  int rb = tid >> 3, cb = (tid & 7) * 4;
  const float* pB[2];
#pragma unroll
  for (int i = 0; i < 2; i++) pB[i] = We + (size_t)(h0 + rb + i * 32) * K + cb;

  int wave = tid >> 6, lane = tid & 63;
  int wm = wave >> 1, wn = wave & 1;
  int lrow = lane & 15, lquad = lane >> 4;

  f32x4 acc[4][2] = {};

  for (int k0 = 0; k0 < K; k0 += 32) {
    uint4 a0 = *reinterpret_cast<const uint4*>(pA0 + k0);
    uint4 a1 = *reinterpret_cast<const uint4*>(pA1 + k0);
    float4 vb[2];
#pragma unroll
    for (int i = 0; i < 2; i++) vb[i] = *reinterpret_cast<const float4*>(pB[i] + k0);
    __syncthreads();
    *reinterpret_cast<uint4*>(&sA[ra * 32 + ca]) = a0;
    *reinterpret_cast<uint4*>(&sA[(ra + 64) * 32 + ca]) = a1;
#pragma unroll
    for (int i = 0; i < 2; i++) {
      short4 s; s.x = f2b(vb[i].x); s.y = f2b(vb[i].y); s.z = f2b(vb[i].z); s.w = f2b(vb[i].w);
      *reinterpret_cast<short4*>(&sB[(rb + i * 32) * 32 + cb]) = s;
    }
    __syncthreads();
    bf16x8 af[4], bf[2];
#pragma unroll
    for (int i = 0; i < 4; i++)
      af[i] = *reinterpret_cast<const bf16x8*>(&sA[(wm * 64 + i * 16 + lrow) * 32 + lquad * 8]);
#pragma unroll
    for (int i = 0; i < 2; i++)
      bf[i] = *reinterpret_cast<const bf16x8*>(&sB[(wn * 32 + i * 16 + lrow) * 32 + lquad * 8]);
#pragma unroll
    for (int mi = 0; mi < 4; mi++)
#pragma unroll
      for (int ni = 0; ni < 2; ni++)
        acc[mi][ni] = __builtin_amdgcn_mfma_f32_16x16x32_bf16(af[mi], bf[ni], acc[mi][ni], 0, 0, 0);
  }

  if (mode == 0) {
#pragma unroll
    for (int mi = 0; mi < 4; mi++)
#pragma unroll
      for (int r = 0; r < 4; r++) {
        int li = wm * 64 + mi * 16 + lquad * 4 + r;
        size_t orow = (size_t)(m0 + li) * HDIM;
#pragma unroll
        for (int ni = 0; ni < 2; ni++)
          out[orow + h0 + wn * 32 + ni * 16 + lrow] = acc[mi][ni][r];
      }
  } else {
#pragma unroll
    for (int mi = 0; mi < 4; mi++)
#pragma unroll
      for (int r = 0; r < 4; r++) {
        int li = wm * 64 + mi * 16 + lquad * 4 + r;
        bool ok = (m0 + li) < count;
        int tok = sTok[li];
        float w = comb[tok * 16 + e];
#pragma unroll
        for (int ni = 0; ni < 2; ni++)
          if (ok) atomicAdd(&out[(size_t)tok * HDIM + h0 + wn * 32 + ni * 16 + lrow],
                            acc[mi][ni][r] * w);
      }
  }
}

extern "C" void kernel_launch(void* const* d_in, const int* in_sizes, int n_in,
                              void* d_out, int out_size, void* d_ws, size_t ws_size,
                              hipStream_t stream) {
  const float* hs  = (const float*)d_in[0];
  const float* gw  = (const float*)d_in[1];
  const float* w1  = (const float*)d_in[2];
  const float* w2  = (const float*)d_in[3];
  const float* sgu = (const float*)d_in[4];
  const float* sd  = (const float*)d_in[5];
  float* out = (float*)d_out;
  char* ws = (char*)d_ws;

  // ws layout
  float*    comb    = (float*)(ws + 0);          // 1024*16*4      = 65536
  unsigned* maskbuf = (unsigned*)(ws + 65536);   // 1024*4         = 4096
  int*      lists   = (int*)(ws + 69632);        // 16*1024*4      = 65536
  int*      counts  = (int*)(ws + 135168);       // 64
  int*      offsets = (int*)(ws + 135232);       // 64
  __hip_bfloat16* Gr = (__hip_bfloat16*)(ws + 262144);              // 6272*1024*2 = 12,845,056
  __hip_bfloat16* Gs = (__hip_bfloat16*)(ws + 262144 + 12845056);   // 1024*2048*2 = 4,194,304
  if (ws_size < (size_t)(262144 + 12845056 + 4194304)) return;  // need ~17.3 MB scratch

  k_router<<<dim3(256), dim3(256), 0, stream>>>(hs, gw, comb, maskbuf);
  k_build_lists<<<dim3(1), dim3(1024), 0, stream>>>(maskbuf, lists, counts, offsets);
  // routed gemm1: g = silu(h@w1g)*（h@w1u), gathered rows, packed by expert
  k_mlp1<<<dim3(16, 8, 16), dim3(256), 0, stream>>>(hs, w1, Gr, lists, counts, offsets, NMOE);
  // shared expert gemm1 over all tokens
  k_mlp1<<<dim3(32, 8, 1), dim3(256), 0, stream>>>(hs, sgu, Gs, nullptr, nullptr, nullptr, NSH);
  // shared gemm2: plain store (fully covers d_out)
  k_mlp2<<<dim3(16, 8, 1), dim3(256), 0, stream>>>(Gs, sd, out, nullptr, nullptr, nullptr, nullptr, NSH, 0);
  // routed gemm2: weighted atomic accumulate on top
  k_mlp2<<<dim3(16, 8, 16), dim3(256), 0, stream>>>(Gr, w2, out, lists, counts, offsets, comb, NMOE, 1);
}